// Round 4
// baseline (325.324 us; speedup 1.0000x reference)
//
#include <hip/hip_runtime.h>

#define N_NODES 20000
#define DEG 6
#define E_EDGES 120000
#define HID 128
#define OUT_D 128
#define EPS_BN 1e-5f

// ws float offsets (stats only; h3 lives in d_out)
#define WS_S0SUM 0
#define WS_S0SQ  80
#define WS_S1SUM 160
#define WS_S1SQ  288
#define WS_FSUM  416
#define WS_FSQ   544
#define WS_STATS_FLOATS 672

// LDS row strides (bf16 elements), padded so 16-lane b128 column reads are <=2-way
#define LDA0 104   // h0s rows (cols 0..79 data, 80..95 zero, 96..103 unused)
#define LDW1 104   // W1^T rows (k 0..79 data, 80..95 zero)
#define LDWG 136   // Wg^T rows (k 0..127 data)
#define LDH1 136   // h1 rows  (cols 0..127 data)

typedef float f32x4 __attribute__((ext_vector_type(4)));
typedef short bf16x8 __attribute__((ext_vector_type(8)));

__device__ __forceinline__ unsigned short f2bf(float f) {
  unsigned u = __float_as_uint(f);
  u += 0x7fffu + ((u >> 16) & 1u);   // RNE
  return (unsigned short)(u >> 16);
}
__device__ __forceinline__ unsigned pack2bf(float a, float b) {
  return (unsigned)f2bf(a) | ((unsigned)f2bf(b) << 16);
}

// ---------------------------------------------------------------- K1: bn0 stats
__global__ __launch_bounds__(256) void k1_bn0_stats(
    const float* __restrict__ node_attr, const float* __restrict__ edge_attr,
    float* __restrict__ ws) {
  __shared__ float red[256];
  const int t = threadIdx.x;
  const int b = blockIdx.x;
  if (b < 128) {  // node cols: per-node stats == per-edge stats (exact 6x repeat)
    const int c = t & 63, rl = t >> 6;
    float s = 0.f, q = 0.f;
    for (int row = b * 4 + rl; row < N_NODES; row += 512) {
      float v = node_attr[row * 64 + c];
      s += v; q += v * v;
    }
    red[t] = s;
    __syncthreads();
    if (t < 64) atomicAdd(&ws[WS_S0SUM + t], red[t] + red[t + 64] + red[t + 128] + red[t + 192]);
    __syncthreads();
    red[t] = q;
    __syncthreads();
    if (t < 64) atomicAdd(&ws[WS_S0SQ + t], red[t] + red[t + 64] + red[t + 128] + red[t + 192]);
  } else {  // edge cols
    const int c = t & 15, rl = t >> 4;
    float s = 0.f, q = 0.f;
    for (int row = (b - 128) * 16 + rl; row < E_EDGES; row += 1024) {
      float v = edge_attr[row * 16 + c];
      s += v; q += v * v;
    }
    red[t] = s;
    __syncthreads();
    if (t < 16) {
      float tot = 0.f;
      #pragma unroll
      for (int k = 0; k < 16; ++k) tot += red[t + 16 * k];
      atomicAdd(&ws[WS_S0SUM + 64 + t], tot);
    }
    __syncthreads();
    red[t] = q;
    __syncthreads();
    if (t < 16) {
      float tot = 0.f;
      #pragma unroll
      for (int k = 0; k < 16; ++k) tot += red[t + 16 * k];
      atomicAdd(&ws[WS_S0SQ + 64 + t], tot);
    }
  }
}

// --------------------------- K2': MFMA GEMM1 -> bn1 column sums (pre-BN, pre-ReLU)
__global__ __launch_bounds__(512) void k2_bn1_stats_mfma(
    const float* __restrict__ node_attr, const float* __restrict__ edge_attr,
    const float* __restrict__ bn0_g, const float* __restrict__ bn0_b,
    const float* __restrict__ W1, float* __restrict__ ws) {
  __shared__ short h0s[96 * LDA0];
  __shared__ short w1t[128 * LDW1];
  __shared__ float sc0[80], sh0[80];
  const int t = threadIdx.x;
  if (t < 80) {
    float cnt = (t < 64) ? (float)N_NODES : (float)E_EDGES;
    float mu = ws[WS_S0SUM + t] / cnt;
    float var = ws[WS_S0SQ + t] / cnt - mu * mu;
    float sc = bn0_g[t] * rsqrtf(var + EPS_BN);
    sc0[t] = sc; sh0[t] = bn0_b[t] - mu * sc;
  }
  // stage W1^T bf16 (coalesced reads: consecutive lanes -> consecutive n)
  for (int i = t; i < 40 * 128; i += 512) {
    int kp = i >> 7, n = i & 127, k = kp * 2;
    *(unsigned*)&w1t[n * LDW1 + k] = pack2bf(W1[k * 128 + n], W1[(k + 1) * 128 + n]);
  }
  for (int i = t; i < 8 * 128; i += 512) {
    int kp = i >> 7, n = i & 127;
    *(unsigned*)&w1t[n * LDW1 + 80 + kp * 2] = 0u;
  }
  __syncthreads();
  const int ebase = blockIdx.x * 96;
  for (int i = t; i < 96 * 40; i += 512) {
    int row = i / 40, pc = i % 40, c = pc * 2;
    int ge = ebase + row;
    float a, b;
    if (c < 64) {
      const float* p = node_attr + (ge / DEG) * 64 + c;
      a = p[0]; b = p[1];
    } else {
      const float* p = edge_attr + ge * 16 + (c - 64);
      a = p[0]; b = p[1];
    }
    a = a * sc0[c] + sh0[c];
    b = b * sc0[c + 1] + sh0[c + 1];
    *(unsigned*)&h0s[row * LDA0 + c] = pack2bf(a, b);
  }
  for (int i = t; i < 96 * 8; i += 512) {
    int row = i >> 3, pc = i & 7;
    *(unsigned*)&h0s[row * LDA0 + 80 + pc * 2] = 0u;
  }
  __syncthreads();
  const int l = t & 63, wid = t >> 6;
  const int wm = wid >> 2, wn = wid & 3;
  const int lm = l & 15, lq = l >> 4;
  const int Mb = wm * 48, Nb = wn * 32;
  f32x4 acc[3][2] = {};
  #pragma unroll
  for (int ks = 0; ks < 3; ++ks) {
    bf16x8 a[3], b[2];
    #pragma unroll
    for (int mt = 0; mt < 3; ++mt)
      a[mt] = *(const bf16x8*)&h0s[(Mb + mt * 16 + lm) * LDA0 + ks * 32 + lq * 8];
    #pragma unroll
    for (int nt = 0; nt < 2; ++nt)
      b[nt] = *(const bf16x8*)&w1t[(Nb + nt * 16 + lm) * LDW1 + ks * 32 + lq * 8];
    #pragma unroll
    for (int mt = 0; mt < 3; ++mt)
      #pragma unroll
      for (int nt = 0; nt < 2; ++nt)
        acc[mt][nt] = __builtin_amdgcn_mfma_f32_16x16x32_bf16(a[mt], b[nt], acc[mt][nt], 0, 0, 0);
  }
  #pragma unroll
  for (int nt = 0; nt < 2; ++nt) {
    float s = 0.f, q = 0.f;
    #pragma unroll
    for (int mt = 0; mt < 3; ++mt)
      #pragma unroll
      for (int r = 0; r < 4; ++r) {
        float v = acc[mt][nt][r];
        s += v; q += v * v;
      }
    s += __shfl_xor(s, 16); s += __shfl_xor(s, 32);
    q += __shfl_xor(q, 16); q += __shfl_xor(q, 32);
    if (lq == 0) {
      int col = Nb + nt * 16 + lm;
      atomicAdd(&ws[WS_S1SUM + col], s);
      atomicAdd(&ws[WS_S1SQ + col], q);
    }
  }
}

// ---- K3': MFMA GEMM1+bn1+relu -> MFMA GEMM2 -> 6x6 attention -> pool -> bnf stats
__global__ __launch_bounds__(512) void k3_fused_mfma(
    const float* __restrict__ node_attr, const float* __restrict__ edge_attr,
    const float* __restrict__ bn0_g, const float* __restrict__ bn0_b,
    const float* __restrict__ W1,
    const float* __restrict__ bn1_g, const float* __restrict__ bn1_b,
    const float* __restrict__ Wg,
    const float* __restrict__ att_src, const float* __restrict__ att_dst,
    const float* __restrict__ gat_bias,
    float* __restrict__ out, float* __restrict__ ws) {
  __shared__ short h0s[96 * LDA0];       // 19968 B
  __shared__ short w1t[128 * LDW1];      // 26624 B
  __shared__ short wgt[128 * LDWG];      // 34816 B
  __shared__ short h1s[96 * LDH1];       // 26112 B
  __shared__ float sc0[80], sh0[80];
  __shared__ float sc1[128], sh1[128];
  __shared__ float asP[4][96], adP[4][96];
  __shared__ float asS[96], adS[96], wS[96];
  __shared__ float alphaL[96][6];
  __shared__ float h3L[16 * 128];        // 8 KB
  __shared__ float red[16][128];         // 8 KB

  const int t = threadIdx.x;
  if (t < 80) {
    float cnt = (t < 64) ? (float)N_NODES : (float)E_EDGES;
    float mu = ws[WS_S0SUM + t] / cnt;
    float var = ws[WS_S0SQ + t] / cnt - mu * mu;
    float sc = bn0_g[t] * rsqrtf(var + EPS_BN);
    sc0[t] = sc; sh0[t] = bn0_b[t] - mu * sc;
  }
  if (t < 128) {
    const float invE = 1.f / (float)E_EDGES;
    float mu = ws[WS_S1SUM + t] * invE;
    float var = ws[WS_S1SQ + t] * invE - mu * mu;
    float sc = bn1_g[t] * rsqrtf(var + EPS_BN);
    sc1[t] = sc; sh1[t] = bn1_b[t] - mu * sc;
  }
  // stage W1^T and Wg^T (bf16, transposed, coalesced global reads)
  for (int i = t; i < 40 * 128; i += 512) {
    int kp = i >> 7, n = i & 127, k = kp * 2;
    *(unsigned*)&w1t[n * LDW1 + k] = pack2bf(W1[k * 128 + n], W1[(k + 1) * 128 + n]);
  }
  for (int i = t; i < 8 * 128; i += 512) {
    int kp = i >> 7, n = i & 127;
    *(unsigned*)&w1t[n * LDW1 + 80 + kp * 2] = 0u;
  }
  for (int i = t; i < 64 * 128; i += 512) {
    int kp = i >> 7, n = i & 127, k = kp * 2;
    *(unsigned*)&wgt[n * LDWG + k] = pack2bf(Wg[k * 128 + n], Wg[(k + 1) * 128 + n]);
  }
  __syncthreads();

  const int l = t & 63, wid = t >> 6;
  const int wm = wid >> 2, wn = wid & 3;
  const int lm = l & 15, lq = l >> 4;
  const int Mb = wm * 48, Nb = wn * 32;
  float scc[2], shc[2], atS[2], atD[2];
  #pragma unroll
  for (int nt = 0; nt < 2; ++nt) {
    int col = Nb + nt * 16 + lm;
    scc[nt] = sc1[col]; shc[nt] = sh1[col];
    atS[nt] = att_src[col]; atD[nt] = att_dst[col];
  }
  const int c4 = (t & 31) * 4, nslot = t >> 5;
  const f32x4 gb = *(const f32x4*)&gat_bias[c4];
  float fs[4] = {0.f, 0.f, 0.f, 0.f}, fq[4] = {0.f, 0.f, 0.f, 0.f};

  for (int g = blockIdx.x; g < E_EDGES / 96; g += 250) {
    __syncthreads();   // guard LDS reuse from previous iteration
    *(f32x4*)&h3L[t * 4] = (f32x4){0.f, 0.f, 0.f, 0.f};
    const int ebase = g * 96;
    for (int i = t; i < 96 * 40; i += 512) {
      int row = i / 40, pc = i % 40, c = pc * 2;
      int ge = ebase + row;
      float a, b;
      if (c < 64) {
        const float* p = node_attr + (ge / DEG) * 64 + c;
        a = p[0]; b = p[1];
      } else {
        const float* p = edge_attr + ge * 16 + (c - 64);
        a = p[0]; b = p[1];
      }
      a = a * sc0[c] + sh0[c];
      b = b * sc0[c + 1] + sh0[c + 1];
      *(unsigned*)&h0s[row * LDA0 + c] = pack2bf(a, b);
    }
    for (int i = t; i < 96 * 8; i += 512) {
      int row = i >> 3, pc = i & 7;
      *(unsigned*)&h0s[row * LDA0 + 80 + pc * 2] = 0u;
    }
    __syncthreads();
    // GEMM1 (K=96 incl. zero pad) -> bn1 -> relu -> h1s (bf16)
    {
      f32x4 acc1[3][2] = {};
      #pragma unroll
      for (int ks = 0; ks < 3; ++ks) {
        bf16x8 a[3], b[2];
        #pragma unroll
        for (int mt = 0; mt < 3; ++mt)
          a[mt] = *(const bf16x8*)&h0s[(Mb + mt * 16 + lm) * LDA0 + ks * 32 + lq * 8];
        #pragma unroll
        for (int nt = 0; nt < 2; ++nt)
          b[nt] = *(const bf16x8*)&w1t[(Nb + nt * 16 + lm) * LDW1 + ks * 32 + lq * 8];
        #pragma unroll
        for (int mt = 0; mt < 3; ++mt)
          #pragma unroll
          for (int nt = 0; nt < 2; ++nt)
            acc1[mt][nt] = __builtin_amdgcn_mfma_f32_16x16x32_bf16(a[mt], b[nt], acc1[mt][nt], 0, 0, 0);
      }
      #pragma unroll
      for (int mt = 0; mt < 3; ++mt)
        #pragma unroll
        for (int nt = 0; nt < 2; ++nt)
          #pragma unroll
          for (int r = 0; r < 4; ++r) {
            int row = Mb + mt * 16 + lq * 4 + r;
            int col = Nb + nt * 16 + lm;
            float v = fmaxf(acc1[mt][nt][r] * scc[nt] + shc[nt], 0.f);
            h1s[row * LDH1 + col] = (short)f2bf(v);
          }
    }
    __syncthreads();
    // GEMM2 (K=128): x kept in regs
    f32x4 acc2[3][2] = {};
    #pragma unroll
    for (int ks = 0; ks < 4; ++ks) {
      bf16x8 a[3], b[2];
      #pragma unroll
      for (int mt = 0; mt < 3; ++mt)
        a[mt] = *(const bf16x8*)&h1s[(Mb + mt * 16 + lm) * LDH1 + ks * 32 + lq * 8];
      #pragma unroll
      for (int nt = 0; nt < 2; ++nt)
        b[nt] = *(const bf16x8*)&wgt[(Nb + nt * 16 + lm) * LDWG + ks * 32 + lq * 8];
      #pragma unroll
      for (int mt = 0; mt < 3; ++mt)
        #pragma unroll
        for (int nt = 0; nt < 2; ++nt)
          acc2[mt][nt] = __builtin_amdgcn_mfma_f32_16x16x32_bf16(a[mt], b[nt], acc2[mt][nt], 0, 0, 0);
    }
    // per-row att dots (this wave's 32 cols), reduce over the 16-lane N-group
    float ps[3][4], pd[3][4];
    #pragma unroll
    for (int mt = 0; mt < 3; ++mt)
      #pragma unroll
      for (int r = 0; r < 4; ++r) {
        ps[mt][r] = acc2[mt][0][r] * atS[0] + acc2[mt][1][r] * atS[1];
        pd[mt][r] = acc2[mt][0][r] * atD[0] + acc2[mt][1][r] * atD[1];
      }
    #pragma unroll
    for (int off = 1; off < 16; off <<= 1)
      #pragma unroll
      for (int mt = 0; mt < 3; ++mt)
        #pragma unroll
        for (int r = 0; r < 4; ++r) {
          ps[mt][r] += __shfl_xor(ps[mt][r], off);
          pd[mt][r] += __shfl_xor(pd[mt][r], off);
        }
    if (lm == 0) {
      #pragma unroll
      for (int mt = 0; mt < 3; ++mt)
        #pragma unroll
        for (int r = 0; r < 4; ++r) {
          int row = Mb + mt * 16 + lq * 4 + r;
          asP[wn][row] = ps[mt][r];
          adP[wn][row] = pd[mt][r];
        }
    }
    __syncthreads();
    if (t < 96) {
      asS[t] = asP[0][t] + asP[1][t] + asP[2][t] + asP[3][t];
      adS[t] = adP[0][t] + adP[1][t] + adP[2][t] + adP[3][t];
    }
    __syncthreads();
    if (t < 96) {  // (node n, dest j): softmax over 6 group members
      int n = t / 6, nb6 = n * 6;
      float ad = adS[t];
      float s6[6], m = -1e30f;
      #pragma unroll
      for (int i = 0; i < 6; ++i) {
        float s = asS[nb6 + i] + ad;
        s = (s > 0.f) ? s : 0.2f * s;
        s6[i] = s; m = fmaxf(m, s);
      }
      float ssum = 0.f, ex[6];
      #pragma unroll
      for (int i = 0; i < 6; ++i) { ex[i] = __expf(s6[i] - m); ssum += ex[i]; }
      float inv = 1.f / (ssum + 1e-16f);
      #pragma unroll
      for (int i = 0; i < 6; ++i) alphaL[t][i] = ex[i] * inv;
    }
    __syncthreads();
    if (t < 96) {  // w_i = sum_j alpha_ij
      int n = t / 6, i = t % 6;
      float w = 0.f;
      #pragma unroll
      for (int j = 0; j < 6; ++j) w += alphaL[n * 6 + j][i];
      wS[t] = w;
    }
    __syncthreads();
    // pool: h3[n] += w_row * x_row
    #pragma unroll
    for (int mt = 0; mt < 3; ++mt)
      #pragma unroll
      for (int r = 0; r < 4; ++r) {
        int row = Mb + mt * 16 + lq * 4 + r;
        float w = wS[row];
        int nl = row / 6;
        #pragma unroll
        for (int nt = 0; nt < 2; ++nt)
          atomicAdd(&h3L[nl * 128 + Nb + nt * 16 + lm], w * acc2[mt][nt][r]);
      }
    __syncthreads();
    // write out + bnf accumulation
    {
      f32x4 v = *(f32x4*)&h3L[nslot * 128 + c4];
      v[0] += 6.f * gb[0]; v[1] += 6.f * gb[1];
      v[2] += 6.f * gb[2]; v[3] += 6.f * gb[3];
      *(f32x4*)&out[(g * 16 + nslot) * OUT_D + c4] = v;
      #pragma unroll
      for (int j = 0; j < 4; ++j) { fs[j] += v[j]; fq[j] += v[j] * v[j]; }
    }
  }
  // bnf column stats
  __syncthreads();
  #pragma unroll
  for (int j = 0; j < 4; ++j) red[nslot][c4 + j] = fs[j];
  __syncthreads();
  if (t < 128) {
    float s = 0.f;
    #pragma unroll
    for (int k = 0; k < 16; ++k) s += red[k][t];
    atomicAdd(&ws[WS_FSUM + t], s);
  }
  __syncthreads();
  #pragma unroll
  for (int j = 0; j < 4; ++j) red[nslot][c4 + j] = fq[j];
  __syncthreads();
  if (t < 128) {
    float s = 0.f;
    #pragma unroll
    for (int k = 0; k < 16; ++k) s += red[k][t];
    atomicAdd(&ws[WS_FSQ + t], s);
  }
}

// ------------------------------------------ K4: final BN applied in-place on out
__global__ __launch_bounds__(256) void k4_final(
    float* __restrict__ out, const float* __restrict__ ws,
    const float* __restrict__ bnf_g, const float* __restrict__ bnf_b) {
  int idx4 = blockIdx.x * 256 + threadIdx.x;
  if (idx4 >= N_NODES * OUT_D / 4) return;
  int c0 = (idx4 & 31) << 2;
  float4 v = ((float4*)out)[idx4];
  float4 fsv = *(const float4*)&ws[WS_FSUM + c0];
  float4 fqv = *(const float4*)&ws[WS_FSQ + c0];
  float4 g4 = *(const float4*)&bnf_g[c0];
  float4 b4 = *(const float4*)&bnf_b[c0];
  const float invN = 1.f / (float)N_NODES;
  float mu, var, sc;
  mu = fsv.x * invN; var = fqv.x * invN - mu * mu; sc = g4.x * rsqrtf(var + EPS_BN);
  v.x = (v.x - mu) * sc + b4.x;
  mu = fsv.y * invN; var = fqv.y * invN - mu * mu; sc = g4.y * rsqrtf(var + EPS_BN);
  v.y = (v.y - mu) * sc + b4.y;
  mu = fsv.z * invN; var = fqv.z * invN - mu * mu; sc = g4.z * rsqrtf(var + EPS_BN);
  v.z = (v.z - mu) * sc + b4.z;
  mu = fsv.w * invN; var = fqv.w * invN - mu * mu; sc = g4.w * rsqrtf(var + EPS_BN);
  v.w = (v.w - mu) * sc + b4.w;
  ((float4*)out)[idx4] = v;
}

extern "C" void kernel_launch(void* const* d_in, const int* in_sizes, int n_in,
                              void* d_out, int out_size, void* d_ws, size_t ws_size,
                              hipStream_t stream) {
  const float* edge_attr = (const float*)d_in[0];
  const float* node_attr = (const float*)d_in[1];
  const float* bn0_g = (const float*)d_in[2];
  const float* bn0_b = (const float*)d_in[3];
  const float* W1    = (const float*)d_in[4];
  const float* bn1_g = (const float*)d_in[5];
  const float* bn1_b = (const float*)d_in[6];
  const float* Wg    = (const float*)d_in[7];
  const float* att_src = (const float*)d_in[8];
  const float* att_dst = (const float*)d_in[9];
  const float* gat_bias = (const float*)d_in[10];
  const float* bnf_g = (const float*)d_in[11];
  const float* bnf_b = (const float*)d_in[12];
  float* ws = (float*)d_ws;
  float* out = (float*)d_out;

  hipMemsetAsync(d_ws, 0, WS_STATS_FLOATS * sizeof(float), stream);
  k1_bn0_stats<<<192, 256, 0, stream>>>(node_attr, edge_attr, ws);
  k2_bn1_stats_mfma<<<E_EDGES / 96, 512, 0, stream>>>(node_attr, edge_attr, bn0_g, bn0_b, W1, ws);
  k3_fused_mfma<<<250, 512, 0, stream>>>(node_attr, edge_attr, bn0_g, bn0_b, W1,
                                         bn1_g, bn1_b, Wg, att_src, att_dst, gat_bias,
                                         out, ws);
  k4_final<<<2500, 256, 0, stream>>>(out, ws, bnf_g, bnf_b);
}

// Round 6
// 253.583 us; speedup vs baseline: 1.2829x; 1.2829x over previous
//
#include <hip/hip_runtime.h>

#define N_NODES 20000
#define DEG 6
#define E_EDGES 120000
#define EPS_BN 1e-5f

// ws float offsets
#define WS_S0SUM 0          // 80
#define WS_S0SQ  80         // 80
#define WS_S1SUM 160        // 8 sets x 128
#define WS_S1SQ  1184       // 8 sets x 128
#define WS_FSUM  2208       // 8 sets x 128
#define WS_FSQ   3232       // 8 sets x 128
#define WS_STATS_FLOATS 4256

// LDS row strides (bf16 elements)
#define LDA0 104   // h0 rows: cols 0..79 data, 80..95 zero-pad, stride pad->104
#define LDH1 136   // h1 rows: cols 0..127

typedef float f32x4 __attribute__((ext_vector_type(4)));
typedef short bf16x8 __attribute__((ext_vector_type(8)));

__device__ __forceinline__ unsigned short f2bf(float f) {
  unsigned u = __float_as_uint(f);
  u += 0x7fffu + ((u >> 16) & 1u);   // RNE
  return (unsigned short)(u >> 16);
}
__device__ __forceinline__ unsigned pack2bf(float a, float b) {
  return (unsigned)f2bf(a) | ((unsigned)f2bf(b) << 16);
}
// Build a B-fragment (16x16x32 bf16) for column `col` of a row-major [K x 128]
// weight, k range [k0, k0+8), zero beyond kmax. Loads are exec-masked (no OOB).
__device__ __forceinline__ bf16x8 load_w_frag(const float* __restrict__ W,
                                              int col, int k0, int kmax) {
  union { bf16x8 v; unsigned u[4]; } tmp;
  #pragma unroll
  for (int p = 0; p < 4; ++p) {
    int k = k0 + 2 * p;
    float a = (k < kmax) ? W[k * 128 + col] : 0.f;
    float b = (k + 1 < kmax) ? W[(k + 1) * 128 + col] : 0.f;
    tmp.u[p] = pack2bf(a, b);
  }
  return tmp.v;
}

// ---------------------------------------------------------------- K1: bn0 stats
__global__ __launch_bounds__(256) void k1_bn0_stats(
    const float* __restrict__ node_attr, const float* __restrict__ edge_attr,
    float* __restrict__ ws) {
  __shared__ float red[256];
  const int t = threadIdx.x;
  const int b = blockIdx.x;
  if (b < 128) {  // node cols (per-node stats == per-edge stats, exact 6x repeat)
    const int c = t & 63, rl = t >> 6;
    float s = 0.f, q = 0.f;
    for (int row = b * 4 + rl; row < N_NODES; row += 512) {
      float v = node_attr[row * 64 + c];
      s += v; q += v * v;
    }
    red[t] = s;
    __syncthreads();
    if (t < 64) atomicAdd(&ws[WS_S0SUM + t], red[t] + red[t + 64] + red[t + 128] + red[t + 192]);
    __syncthreads();
    red[t] = q;
    __syncthreads();
    if (t < 64) atomicAdd(&ws[WS_S0SQ + t], red[t] + red[t + 64] + red[t + 128] + red[t + 192]);
  } else {  // edge cols
    const int c = t & 15, rl = t >> 4;
    float s = 0.f, q = 0.f;
    for (int row = (b - 128) * 16 + rl; row < E_EDGES; row += 2048) {
      float v = edge_attr[row * 16 + c];
      s += v; q += v * v;
    }
    red[t] = s;
    __syncthreads();
    if (t < 16) {
      float tot = 0.f;
      #pragma unroll
      for (int k = 0; k < 16; ++k) tot += red[t + 16 * k];
      atomicAdd(&ws[WS_S0SUM + 64 + t], tot);
    }
    __syncthreads();
    red[t] = q;
    __syncthreads();
    if (t < 16) {
      float tot = 0.f;
      #pragma unroll
      for (int k = 0; k < 16; ++k) tot += red[t + 16 * k];
      atomicAdd(&ws[WS_S0SQ + 64 + t], tot);
    }
  }
}

// -------- K2: MFMA GEMM1 (48-edge tile) -> bn1 column sums (8-way split atomics)
__global__ __launch_bounds__(256, 4) void k2_bn1_stats(
    const float* __restrict__ node_attr, const float* __restrict__ edge_attr,
    const float* __restrict__ bn0_g, const float* __restrict__ bn0_b,
    const float* __restrict__ W1, float* __restrict__ ws) {
  __shared__ short h0s[48 * LDA0];
  __shared__ float sc0[80], sh0[80];
  const int t = threadIdx.x;
  if (t < 80) {
    float cnt = (t < 64) ? (float)N_NODES : (float)E_EDGES;
    float mu = ws[WS_S0SUM + t] / cnt;
    float var = ws[WS_S0SQ + t] / cnt - mu * mu;
    float sc = bn0_g[t] * rsqrtf(var + EPS_BN);
    sc0[t] = sc; sh0[t] = bn0_b[t] - mu * sc;
  }
  const int l = t & 63, wid = t >> 6;      // 4 waves = 4 N-slices of 32
  const int lm = l & 15, lq = l >> 4;
  const int Nb = wid * 32;
  // W1^T fragments in registers (once)
  bf16x8 w1f[2][3];
  #pragma unroll
  for (int nt = 0; nt < 2; ++nt)
    #pragma unroll
    for (int ks = 0; ks < 3; ++ks)
      w1f[nt][ks] = load_w_frag(W1, Nb + nt * 16 + lm, ks * 32 + lq * 8, 80);
  __syncthreads();
  const int ebase = blockIdx.x * 48;
  for (int i = t; i < 48 * 40; i += 256) {
    int row = i / 40, pc = i % 40, c = pc * 2;
    int ge = ebase + row;
    float a, b;
    if (c < 64) {
      const float* p = node_attr + (ge / DEG) * 64 + c;
      a = p[0]; b = p[1];
    } else {
      const float* p = edge_attr + ge * 16 + (c - 64);
      a = p[0]; b = p[1];
    }
    a = a * sc0[c] + sh0[c];
    b = b * sc0[c + 1] + sh0[c + 1];
    *(unsigned*)&h0s[row * LDA0 + c] = pack2bf(a, b);
  }
  for (int i = t; i < 48 * 8; i += 256) {
    int row = i >> 3, pc = i & 7;
    *(unsigned*)&h0s[row * LDA0 + 80 + pc * 2] = 0u;
  }
  __syncthreads();
  f32x4 acc[3][2] = {};
  #pragma unroll
  for (int ks = 0; ks < 3; ++ks) {
    bf16x8 a[3];
    #pragma unroll
    for (int mt = 0; mt < 3; ++mt)
      a[mt] = *(const bf16x8*)&h0s[(mt * 16 + lm) * LDA0 + ks * 32 + lq * 8];
    #pragma unroll
    for (int mt = 0; mt < 3; ++mt)
      #pragma unroll
      for (int nt = 0; nt < 2; ++nt)
        acc[mt][nt] = __builtin_amdgcn_mfma_f32_16x16x32_bf16(a[mt], w1f[nt][ks], acc[mt][nt], 0, 0, 0);
  }
  const int set = blockIdx.x & 7;
  #pragma unroll
  for (int nt = 0; nt < 2; ++nt) {
    float s = 0.f, q = 0.f;
    #pragma unroll
    for (int mt = 0; mt < 3; ++mt)
      #pragma unroll
      for (int r = 0; r < 4; ++r) {
        float v = acc[mt][nt][r];
        s += v; q += v * v;
      }
    s += __shfl_xor(s, 16); s += __shfl_xor(s, 32);
    q += __shfl_xor(q, 16); q += __shfl_xor(q, 32);
    if (l < 16) {
      int col = Nb + nt * 16 + lm;
      atomicAdd(&ws[WS_S1SUM + set * 128 + col], s);
      atomicAdd(&ws[WS_S1SQ + set * 128 + col], q);
    }
  }
}

// ---- K3: 48-edge tile: GEMM1+bn1+relu -> GEMM2 -> 6x6 attention -> pool -> stats
__global__ __launch_bounds__(256, 4) void k3_fused(
    const float* __restrict__ node_attr, const float* __restrict__ edge_attr,
    const float* __restrict__ bn0_g, const float* __restrict__ bn0_b,
    const float* __restrict__ W1,
    const float* __restrict__ bn1_g, const float* __restrict__ bn1_b,
    const float* __restrict__ Wg,
    const float* __restrict__ att_src, const float* __restrict__ att_dst,
    const float* __restrict__ gat_bias,
    float* __restrict__ out, float* __restrict__ ws) {
  __shared__ short h0s[48 * LDA0];         // 9984 B
  __shared__ short h1s[48 * LDH1];         // 13056 B
  __shared__ float sc0[80], sh0[80];
  __shared__ float sc1[128], sh1[128];
  __shared__ float asP[4][48], adP[4][48];
  __shared__ float asS[48], adS[48], wS[48];
  __shared__ float alphaL[48][6];
  __shared__ float h3L[8 * 128];           // 4 KB
  __shared__ float red[8][128];            // 4 KB

  const int t = threadIdx.x;
  if (t < 80) {
    float cnt = (t < 64) ? (float)N_NODES : (float)E_EDGES;
    float mu = ws[WS_S0SUM + t] / cnt;
    float var = ws[WS_S0SQ + t] / cnt - mu * mu;
    float sc = bn0_g[t] * rsqrtf(var + EPS_BN);
    sc0[t] = sc; sh0[t] = bn0_b[t] - mu * sc;
  }
  if (t < 128) {
    float s = 0.f, q = 0.f;
    #pragma unroll
    for (int st = 0; st < 8; ++st) {
      s += ws[WS_S1SUM + st * 128 + t];
      q += ws[WS_S1SQ + st * 128 + t];
    }
    const float invE = 1.f / (float)E_EDGES;
    float mu = s * invE;
    float var = q * invE - mu * mu;
    float sc = bn1_g[t] * rsqrtf(var + EPS_BN);
    sc1[t] = sc; sh1[t] = bn1_b[t] - mu * sc;
  }
  *(f32x4*)&h3L[t * 4] = (f32x4){0.f, 0.f, 0.f, 0.f};

  const int l = t & 63, wid = t >> 6;      // 4 waves = 4 N-slices of 32
  const int lm = l & 15, lq = l >> 4;
  const int Nb = wid * 32;
  // weight fragments in registers (per block, read from L2)
  bf16x8 w1f[2][3], wgf[2][4];
  #pragma unroll
  for (int nt = 0; nt < 2; ++nt) {
    #pragma unroll
    for (int ks = 0; ks < 3; ++ks)
      w1f[nt][ks] = load_w_frag(W1, Nb + nt * 16 + lm, ks * 32 + lq * 8, 80);
    #pragma unroll
    for (int ks = 0; ks < 4; ++ks)
      wgf[nt][ks] = load_w_frag(Wg, Nb + nt * 16 + lm, ks * 32 + lq * 8, 128);
  }
  float atS[2], atD[2];
  #pragma unroll
  for (int nt = 0; nt < 2; ++nt) {
    int col = Nb + nt * 16 + lm;
    atS[nt] = att_src[col]; atD[nt] = att_dst[col];
  }
  __syncthreads();

  float scc[2], shc[2];
  #pragma unroll
  for (int nt = 0; nt < 2; ++nt) {
    int col = Nb + nt * 16 + lm;
    scc[nt] = sc1[col]; shc[nt] = sh1[col];
  }
  // stage h0 (bn0-applied, bf16)
  const int ebase = blockIdx.x * 48;
  for (int i = t; i < 48 * 40; i += 256) {
    int row = i / 40, pc = i % 40, c = pc * 2;
    int ge = ebase + row;
    float a, b;
    if (c < 64) {
      const float* p = node_attr + (ge / DEG) * 64 + c;
      a = p[0]; b = p[1];
    } else {
      const float* p = edge_attr + ge * 16 + (c - 64);
      a = p[0]; b = p[1];
    }
    a = a * sc0[c] + sh0[c];
    b = b * sc0[c + 1] + sh0[c + 1];
    *(unsigned*)&h0s[row * LDA0 + c] = pack2bf(a, b);
  }
  for (int i = t; i < 48 * 8; i += 256) {
    int row = i >> 3, pc = i & 7;
    *(unsigned*)&h0s[row * LDA0 + 80 + pc * 2] = 0u;
  }
  __syncthreads();
  // GEMM1 -> bn1 -> relu -> h1s
  {
    f32x4 acc1[3][2] = {};
    #pragma unroll
    for (int ks = 0; ks < 3; ++ks) {
      bf16x8 a[3];
      #pragma unroll
      for (int mt = 0; mt < 3; ++mt)
        a[mt] = *(const bf16x8*)&h0s[(mt * 16 + lm) * LDA0 + ks * 32 + lq * 8];
      #pragma unroll
      for (int mt = 0; mt < 3; ++mt)
        #pragma unroll
        for (int nt = 0; nt < 2; ++nt)
          acc1[mt][nt] = __builtin_amdgcn_mfma_f32_16x16x32_bf16(a[mt], w1f[nt][ks], acc1[mt][nt], 0, 0, 0);
    }
    #pragma unroll
    for (int mt = 0; mt < 3; ++mt)
      #pragma unroll
      for (int nt = 0; nt < 2; ++nt)
        #pragma unroll
        for (int r = 0; r < 4; ++r) {
          int row = mt * 16 + lq * 4 + r;
          int col = Nb + nt * 16 + lm;
          float v = fmaxf(acc1[mt][nt][r] * scc[nt] + shc[nt], 0.f);
          h1s[row * LDH1 + col] = (short)f2bf(v);
        }
  }
  __syncthreads();
  // GEMM2 (x stays in registers)
  f32x4 acc2[3][2] = {};
  #pragma unroll
  for (int ks = 0; ks < 4; ++ks) {
    bf16x8 a[3];
    #pragma unroll
    for (int mt = 0; mt < 3; ++mt)
      a[mt] = *(const bf16x8*)&h1s[(mt * 16 + lm) * LDH1 + ks * 32 + lq * 8];
    #pragma unroll
    for (int mt = 0; mt < 3; ++mt)
      #pragma unroll
      for (int nt = 0; nt < 2; ++nt)
        acc2[mt][nt] = __builtin_amdgcn_mfma_f32_16x16x32_bf16(a[mt], wgf[nt][ks], acc2[mt][nt], 0, 0, 0);
  }
  // per-row att dots over this wave's 32 cols; reduce across the 16-lane groups
  {
    float ps[3][4], pd[3][4];
    #pragma unroll
    for (int mt = 0; mt < 3; ++mt)
      #pragma unroll
      for (int r = 0; r < 4; ++r) {
        ps[mt][r] = acc2[mt][0][r] * atS[0] + acc2[mt][1][r] * atS[1];
        pd[mt][r] = acc2[mt][0][r] * atD[0] + acc2[mt][1][r] * atD[1];
      }
    #pragma unroll
    for (int off = 1; off < 16; off <<= 1)
      #pragma unroll
      for (int mt = 0; mt < 3; ++mt)
        #pragma unroll
        for (int r = 0; r < 4; ++r) {
          ps[mt][r] += __shfl_xor(ps[mt][r], off);
          pd[mt][r] += __shfl_xor(pd[mt][r], off);
        }
    if (lm == 0) {
      #pragma unroll
      for (int mt = 0; mt < 3; ++mt)
        #pragma unroll
        for (int r = 0; r < 4; ++r) {
          int row = mt * 16 + lq * 4 + r;
          asP[wid][row] = ps[mt][r];
          adP[wid][row] = pd[mt][r];
        }
    }
  }
  __syncthreads();
  if (t < 48) {
    asS[t] = asP[0][t] + asP[1][t] + asP[2][t] + asP[3][t];
    adS[t] = adP[0][t] + adP[1][t] + adP[2][t] + adP[3][t];
  }
  __syncthreads();
  if (t < 48) {  // (node n, dest j): softmax over the 6 group members
    int n = t / 6, nb6 = n * 6;
    float ad = adS[t];
    float s6[6], m = -1e30f;
    #pragma unroll
    for (int i = 0; i < 6; ++i) {
      float s = asS[nb6 + i] + ad;
      s = (s > 0.f) ? s : 0.2f * s;
      s6[i] = s; m = fmaxf(m, s);
    }
    float ssum = 0.f, ex[6];
    #pragma unroll
    for (int i = 0; i < 6; ++i) { ex[i] = __expf(s6[i] - m); ssum += ex[i]; }
    float inv = 1.f / (ssum + 1e-16f);
    #pragma unroll
    for (int i = 0; i < 6; ++i) alphaL[t][i] = ex[i] * inv;
  }
  __syncthreads();
  if (t < 48) {  // w_i = sum_j alpha_ij
    int n = t / 6, i = t % 6;
    float w = 0.f;
    #pragma unroll
    for (int j = 0; j < 6; ++j) w += alphaL[n * 6 + j][i];
    wS[t] = w;
  }
  __syncthreads();
  // pool: h3[n] += w_row * x_row
  #pragma unroll
  for (int mt = 0; mt < 3; ++mt)
    #pragma unroll
    for (int r = 0; r < 4; ++r) {
      int row = mt * 16 + lq * 4 + r;
      float w = wS[row];
      int nl = row / 6;
      #pragma unroll
      for (int nt = 0; nt < 2; ++nt)
        atomicAdd(&h3L[nl * 128 + Nb + nt * 16 + lm], w * acc2[mt][nt][r]);
    }
  __syncthreads();
  // write out + bnf stats (8-way split atomics)
  const int c4 = (t & 31) * 4, nslot = t >> 5;
  f32x4 v = *(f32x4*)&h3L[nslot * 128 + c4];
  const f32x4 gb = *(const f32x4*)&gat_bias[c4];
  v[0] += 6.f * gb[0]; v[1] += 6.f * gb[1];
  v[2] += 6.f * gb[2]; v[3] += 6.f * gb[3];
  *(f32x4*)&out[(blockIdx.x * 8 + nslot) * 128 + c4] = v;
  const int set = blockIdx.x & 7;
  #pragma unroll
  for (int j = 0; j < 4; ++j) red[nslot][c4 + j] = v[j];
  __syncthreads();
  if (t < 128) {
    float s = 0.f;
    #pragma unroll
    for (int k = 0; k < 8; ++k) s += red[k][t];
    atomicAdd(&ws[WS_FSUM + set * 128 + t], s);
  }
  __syncthreads();
  #pragma unroll
  for (int j = 0; j < 4; ++j) red[nslot][c4 + j] = v[j] * v[j];
  __syncthreads();
  if (t < 128) {
    float s = 0.f;
    #pragma unroll
    for (int k = 0; k < 8; ++k) s += red[k][t];
    atomicAdd(&ws[WS_FSQ + set * 128 + t], s);
  }
}

// ------------------------------------------ K4: final BN applied in-place on out
__global__ __launch_bounds__(256) void k4_final(
    float* __restrict__ out, const float* __restrict__ ws,
    const float* __restrict__ bnf_g, const float* __restrict__ bnf_b) {
  int idx4 = blockIdx.x * 256 + threadIdx.x;
  if (idx4 >= N_NODES * 128 / 4) return;
  int c0 = (idx4 & 31) << 2;
  float4 v = ((float4*)out)[idx4];
  float4 fsv = {0.f, 0.f, 0.f, 0.f}, fqv = {0.f, 0.f, 0.f, 0.f};
  #pragma unroll
  for (int s = 0; s < 8; ++s) {
    float4 a = *(const float4*)&ws[WS_FSUM + s * 128 + c0];
    float4 b = *(const float4*)&ws[WS_FSQ + s * 128 + c0];
    fsv.x += a.x; fsv.y += a.y; fsv.z += a.z; fsv.w += a.w;
    fqv.x += b.x; fqv.y += b.y; fqv.z += b.z; fqv.w += b.w;
  }
  float4 g4 = *(const float4*)&bnf_g[c0];
  float4 b4 = *(const float4*)&bnf_b[c0];
  const float invN = 1.f / (float)N_NODES;
  float mu, var, sc;
  mu = fsv.x * invN; var = fqv.x * invN - mu * mu; sc = g4.x * rsqrtf(var + EPS_BN);
  v.x = (v.x - mu) * sc + b4.x;
  mu = fsv.y * invN; var = fqv.y * invN - mu * mu; sc = g4.y * rsqrtf(var + EPS_BN);
  v.y = (v.y - mu) * sc + b4.y;
  mu = fsv.z * invN; var = fqv.z * invN - mu * mu; sc = g4.z * rsqrtf(var + EPS_BN);
  v.z = (v.z - mu) * sc + b4.z;
  mu = fsv.w * invN; var = fqv.w * invN - mu * mu; sc = g4.w * rsqrtf(var + EPS_BN);
  v.w = (v.w - mu) * sc + b4.w;
  ((float4*)out)[idx4] = v;
}

extern "C" void kernel_launch(void* const* d_in, const int* in_sizes, int n_in,
                              void* d_out, int out_size, void* d_ws, size_t ws_size,
                              hipStream_t stream) {
  const float* edge_attr = (const float*)d_in[0];
  const float* node_attr = (const float*)d_in[1];
  const float* bn0_g = (const float*)d_in[2];
  const float* bn0_b = (const float*)d_in[3];
  const float* W1    = (const float*)d_in[4];
  const float* bn1_g = (const float*)d_in[5];
  const float* bn1_b = (const float*)d_in[6];
  const float* Wg    = (const float*)d_in[7];
  const float* att_src = (const float*)d_in[8];
  const float* att_dst = (const float*)d_in[9];
  const float* gat_bias = (const float*)d_in[10];
  const float* bnf_g = (const float*)d_in[11];
  const float* bnf_b = (const float*)d_in[12];
  float* ws = (float*)d_ws;
  float* out = (float*)d_out;

  hipMemsetAsync(d_ws, 0, WS_STATS_FLOATS * sizeof(float), stream);
  k1_bn0_stats<<<256, 256, 0, stream>>>(node_attr, edge_attr, ws);
  k2_bn1_stats<<<E_EDGES / 48, 256, 0, stream>>>(node_attr, edge_attr, bn0_g, bn0_b, W1, ws);
  k3_fused<<<E_EDGES / 48, 256, 0, stream>>>(node_attr, edge_attr, bn0_g, bn0_b, W1,
                                             bn1_g, bn1_b, Wg, att_src, att_dst, gat_bias,
                                             out, ws);
  k4_final<<<2500, 256, 0, stream>>>(out, ws, bnf_g, bnf_b);
}

// Round 7
// 249.968 us; speedup vs baseline: 1.3015x; 1.0145x over previous
//
#include <hip/hip_runtime.h>

#define N_NODES 20000
#define DEG 6
#define E_EDGES 120000
#define EPS_BN 1e-5f

// ws float offsets
#define WS_S0SUM 0          // 80
#define WS_S0SQ  80         // 80
#define WS_S1SUM 160        // 8 sets x 128
#define WS_S1SQ  1184       // 8 sets x 128
#define WS_FSUM  2208       // 8 sets x 128
#define WS_FSQ   3232       // 8 sets x 128
#define WS_STATS_FLOATS 4256
// pre-transposed bf16 weights (written by k0_prep, never memset)
#define WS_WT1   4256       // 128 cols x 96 ks (bf16) = 6144 floats
#define WS_WGT   10400      // 128 cols x 128 ks (bf16) = 8192 floats
// total ws usage: 18592 floats = 74.4 KB

// LDS row strides (bf16 elements)
#define LDA0 104   // h0 rows: cols 0..79 data, 80..95 zero-pad, stride pad->104
#define LDH1 136   // h1 rows: cols 0..127

typedef float f32x4 __attribute__((ext_vector_type(4)));
typedef short bf16x8 __attribute__((ext_vector_type(8)));

__device__ __forceinline__ unsigned short f2bf(float f) {
  unsigned u = __float_as_uint(f);
  u += 0x7fffu + ((u >> 16) & 1u);   // RNE
  return (unsigned short)(u >> 16);
}
__device__ __forceinline__ unsigned pack2bf(float a, float b) {
  return (unsigned)f2bf(a) | ((unsigned)f2bf(b) << 16);
}

// ---------------- K0: pre-transpose weights to bf16 in ws (one-time, tiny)
__global__ __launch_bounds__(256) void k0_prep(
    const float* __restrict__ W1, const float* __restrict__ Wg,
    float* __restrict__ ws) {
  short* wt1 = (short*)(ws + WS_WT1);
  short* wgt = (short*)(ws + WS_WGT);
  const int t0 = blockIdx.x * 256 + threadIdx.x;
  for (int i = t0; i < 128 * 96; i += 32 * 256) {
    int col = i / 96, k = i % 96;
    wt1[i] = (k < 80) ? (short)f2bf(W1[k * 128 + col]) : (short)0;
  }
  for (int i = t0; i < 128 * 128; i += 32 * 256) {
    int col = i >> 7, k = i & 127;
    wgt[i] = (short)f2bf(Wg[k * 128 + col]);
  }
}

// ---------------------------------------------------------------- K1: bn0 stats
__global__ __launch_bounds__(256) void k1_bn0_stats(
    const float* __restrict__ node_attr, const float* __restrict__ edge_attr,
    float* __restrict__ ws) {
  __shared__ float red[256];
  const int t = threadIdx.x;
  const int b = blockIdx.x;
  if (b < 128) {  // node cols (per-node stats == per-edge stats, exact 6x repeat)
    const int c = t & 63, rl = t >> 6;
    float s = 0.f, q = 0.f;
    for (int row = b * 4 + rl; row < N_NODES; row += 512) {
      float v = node_attr[row * 64 + c];
      s += v; q += v * v;
    }
    red[t] = s;
    __syncthreads();
    if (t < 64) atomicAdd(&ws[WS_S0SUM + t], red[t] + red[t + 64] + red[t + 128] + red[t + 192]);
    __syncthreads();
    red[t] = q;
    __syncthreads();
    if (t < 64) atomicAdd(&ws[WS_S0SQ + t], red[t] + red[t + 64] + red[t + 128] + red[t + 192]);
  } else {  // edge cols
    const int c = t & 15, rl = t >> 4;
    float s = 0.f, q = 0.f;
    for (int row = (b - 128) * 16 + rl; row < E_EDGES; row += 2048) {
      float v = edge_attr[row * 16 + c];
      s += v; q += v * v;
    }
    red[t] = s;
    __syncthreads();
    if (t < 16) {
      float tot = 0.f;
      #pragma unroll
      for (int k = 0; k < 16; ++k) tot += red[t + 16 * k];
      atomicAdd(&ws[WS_S0SUM + 64 + t], tot);
    }
    __syncthreads();
    red[t] = q;
    __syncthreads();
    if (t < 16) {
      float tot = 0.f;
      #pragma unroll
      for (int k = 0; k < 16; ++k) tot += red[t + 16 * k];
      atomicAdd(&ws[WS_S0SQ + 64 + t], tot);
    }
  }
}

// -------- K2: MFMA GEMM1 (48-edge tile) -> bn1 column sums (8-way split atomics)
__global__ __launch_bounds__(256, 2) void k2_bn1_stats(
    const float* __restrict__ node_attr, const float* __restrict__ edge_attr,
    const float* __restrict__ bn0_g, const float* __restrict__ bn0_b,
    float* __restrict__ ws) {
  __shared__ short h0s[48 * LDA0];
  __shared__ float sc0[80], sh0[80];
  const int t = threadIdx.x;
  if (t < 80) {
    float cnt = (t < 64) ? (float)N_NODES : (float)E_EDGES;
    float mu = ws[WS_S0SUM + t] / cnt;
    float var = ws[WS_S0SQ + t] / cnt - mu * mu;
    float sc = bn0_g[t] * rsqrtf(var + EPS_BN);
    sc0[t] = sc; sh0[t] = bn0_b[t] - mu * sc;
  }
  const int l = t & 63, wid = t >> 6;      // 4 waves = 4 N-slices of 32
  const int lm = l & 15, lq = l >> 4;
  const int Nb = wid * 32;
  // W1^T fragments: one 16B load each from pre-transposed bf16
  const short* wt1 = (const short*)(ws + WS_WT1);
  bf16x8 w1f[2][3];
  #pragma unroll
  for (int nt = 0; nt < 2; ++nt)
    #pragma unroll
    for (int ks = 0; ks < 3; ++ks)
      w1f[nt][ks] = *(const bf16x8*)&wt1[(Nb + nt * 16 + lm) * 96 + ks * 32 + lq * 8];
  __syncthreads();
  const int ebase = blockIdx.x * 48;
  for (int i = t; i < 48 * 40; i += 256) {
    int row = i / 40, pc = i % 40, c = pc * 2;
    int ge = ebase + row;
    float a, b;
    if (c < 64) {
      const float* p = node_attr + (ge / DEG) * 64 + c;
      a = p[0]; b = p[1];
    } else {
      const float* p = edge_attr + ge * 16 + (c - 64);
      a = p[0]; b = p[1];
    }
    a = a * sc0[c] + sh0[c];
    b = b * sc0[c + 1] + sh0[c + 1];
    *(unsigned*)&h0s[row * LDA0 + c] = pack2bf(a, b);
  }
  for (int i = t; i < 48 * 8; i += 256) {
    int row = i >> 3, pc = i & 7;
    *(unsigned*)&h0s[row * LDA0 + 80 + pc * 2] = 0u;
  }
  __syncthreads();
  f32x4 acc[3][2] = {};
  #pragma unroll
  for (int ks = 0; ks < 3; ++ks) {
    bf16x8 a[3];
    #pragma unroll
    for (int mt = 0; mt < 3; ++mt)
      a[mt] = *(const bf16x8*)&h0s[(mt * 16 + lm) * LDA0 + ks * 32 + lq * 8];
    #pragma unroll
    for (int mt = 0; mt < 3; ++mt)
      #pragma unroll
      for (int nt = 0; nt < 2; ++nt)
        acc[mt][nt] = __builtin_amdgcn_mfma_f32_16x16x32_bf16(a[mt], w1f[nt][ks], acc[mt][nt], 0, 0, 0);
  }
  const int set = blockIdx.x & 7;
  #pragma unroll
  for (int nt = 0; nt < 2; ++nt) {
    float s = 0.f, q = 0.f;
    #pragma unroll
    for (int mt = 0; mt < 3; ++mt)
      #pragma unroll
      for (int r = 0; r < 4; ++r) {
        float v = acc[mt][nt][r];
        s += v; q += v * v;
      }
    s += __shfl_xor(s, 16); s += __shfl_xor(s, 32);
    q += __shfl_xor(q, 16); q += __shfl_xor(q, 32);
    if (l < 16) {
      int col = Nb + nt * 16 + lm;
      atomicAdd(&ws[WS_S1SUM + set * 128 + col], s);
      atomicAdd(&ws[WS_S1SQ + set * 128 + col], q);
    }
  }
}

// ---- K3: 48-edge tile: GEMM1+bn1+relu -> GEMM2 -> 6x6 attention -> pool -> stats
__global__ __launch_bounds__(256, 2) void k3_fused(
    const float* __restrict__ node_attr, const float* __restrict__ edge_attr,
    const float* __restrict__ bn0_g, const float* __restrict__ bn0_b,
    const float* __restrict__ bn1_g, const float* __restrict__ bn1_b,
    const float* __restrict__ att_src, const float* __restrict__ att_dst,
    const float* __restrict__ gat_bias,
    float* __restrict__ out, float* __restrict__ ws) {
  __shared__ short h0s[48 * LDA0];         // 9984 B
  __shared__ short h1s[48 * LDH1];         // 13056 B
  __shared__ float sc0[80], sh0[80];
  __shared__ float sc1[128], sh1[128];
  __shared__ float asP[4][48], adP[4][48];
  __shared__ float asS[48], adS[48], wS[48];
  __shared__ float alphaL[48][6];
  __shared__ float h3L[8 * 128];           // 4 KB
  __shared__ float red[8][128];            // 4 KB

  const int t = threadIdx.x;
  if (t < 80) {
    float cnt = (t < 64) ? (float)N_NODES : (float)E_EDGES;
    float mu = ws[WS_S0SUM + t] / cnt;
    float var = ws[WS_S0SQ + t] / cnt - mu * mu;
    float sc = bn0_g[t] * rsqrtf(var + EPS_BN);
    sc0[t] = sc; sh0[t] = bn0_b[t] - mu * sc;
  }
  if (t < 128) {
    float s = 0.f, q = 0.f;
    #pragma unroll
    for (int st = 0; st < 8; ++st) {
      s += ws[WS_S1SUM + st * 128 + t];
      q += ws[WS_S1SQ + st * 128 + t];
    }
    const float invE = 1.f / (float)E_EDGES;
    float mu = s * invE;
    float var = q * invE - mu * mu;
    float sc = bn1_g[t] * rsqrtf(var + EPS_BN);
    sc1[t] = sc; sh1[t] = bn1_b[t] - mu * sc;
  }
  *(f32x4*)&h3L[t * 4] = (f32x4){0.f, 0.f, 0.f, 0.f};

  const int l = t & 63, wid = t >> 6;      // 4 waves = 4 N-slices of 32
  const int lm = l & 15, lq = l >> 4;
  const int Nb = wid * 32;
  const short* wt1 = (const short*)(ws + WS_WT1);
  const short* wgt = (const short*)(ws + WS_WGT);
  const int ebase = blockIdx.x * 48;
  __syncthreads();   // stats + h3L visible

  // ---------------- Phase 1: GEMM1 -> bn1 -> relu -> h1s (w1f live only here)
  {
    bf16x8 w1f[2][3];
    #pragma unroll
    for (int nt = 0; nt < 2; ++nt)
      #pragma unroll
      for (int ks = 0; ks < 3; ++ks)
        w1f[nt][ks] = *(const bf16x8*)&wt1[(Nb + nt * 16 + lm) * 96 + ks * 32 + lq * 8];
    float scc[2], shc[2];
    #pragma unroll
    for (int nt = 0; nt < 2; ++nt) {
      int col = Nb + nt * 16 + lm;
      scc[nt] = sc1[col]; shc[nt] = sh1[col];
    }
    // stage h0 (bn0-applied, bf16)
    for (int i = t; i < 48 * 40; i += 256) {
      int row = i / 40, pc = i % 40, c = pc * 2;
      int ge = ebase + row;
      float a, b;
      if (c < 64) {
        const float* p = node_attr + (ge / DEG) * 64 + c;
        a = p[0]; b = p[1];
      } else {
        const float* p = edge_attr + ge * 16 + (c - 64);
        a = p[0]; b = p[1];
      }
      a = a * sc0[c] + sh0[c];
      b = b * sc0[c + 1] + sh0[c + 1];
      *(unsigned*)&h0s[row * LDA0 + c] = pack2bf(a, b);
    }
    for (int i = t; i < 48 * 8; i += 256) {
      int row = i >> 3, pc = i & 7;
      *(unsigned*)&h0s[row * LDA0 + 80 + pc * 2] = 0u;
    }
    __syncthreads();
    f32x4 acc1[3][2] = {};
    #pragma unroll
    for (int ks = 0; ks < 3; ++ks) {
      bf16x8 a[3];
      #pragma unroll
      for (int mt = 0; mt < 3; ++mt)
        a[mt] = *(const bf16x8*)&h0s[(mt * 16 + lm) * LDA0 + ks * 32 + lq * 8];
      #pragma unroll
      for (int mt = 0; mt < 3; ++mt)
        #pragma unroll
        for (int nt = 0; nt < 2; ++nt)
          acc1[mt][nt] = __builtin_amdgcn_mfma_f32_16x16x32_bf16(a[mt], w1f[nt][ks], acc1[mt][nt], 0, 0, 0);
    }
    #pragma unroll
    for (int mt = 0; mt < 3; ++mt)
      #pragma unroll
      for (int nt = 0; nt < 2; ++nt)
        #pragma unroll
        for (int r = 0; r < 4; ++r) {
          int row = mt * 16 + lq * 4 + r;
          int col = Nb + nt * 16 + lm;
          float v = fmaxf(acc1[mt][nt][r] * scc[nt] + shc[nt], 0.f);
          h1s[row * LDH1 + col] = (short)f2bf(v);
        }
  }
  __syncthreads();

  // ---------------- Phase 2: GEMM2 (wgf loaded only now; x stays in registers)
  bf16x8 wgf[2][4];
  #pragma unroll
  for (int nt = 0; nt < 2; ++nt)
    #pragma unroll
    for (int ks = 0; ks < 4; ++ks)
      wgf[nt][ks] = *(const bf16x8*)&wgt[(Nb + nt * 16 + lm) * 128 + ks * 32 + lq * 8];
  float atS[2], atD[2];
  #pragma unroll
  for (int nt = 0; nt < 2; ++nt) {
    int col = Nb + nt * 16 + lm;
    atS[nt] = att_src[col]; atD[nt] = att_dst[col];
  }
  f32x4 acc2[3][2] = {};
  #pragma unroll
  for (int ks = 0; ks < 4; ++ks) {
    bf16x8 a[3];
    #pragma unroll
    for (int mt = 0; mt < 3; ++mt)
      a[mt] = *(const bf16x8*)&h1s[(mt * 16 + lm) * LDH1 + ks * 32 + lq * 8];
    #pragma unroll
    for (int mt = 0; mt < 3; ++mt)
      #pragma unroll
      for (int nt = 0; nt < 2; ++nt)
        acc2[mt][nt] = __builtin_amdgcn_mfma_f32_16x16x32_bf16(a[mt], wgf[nt][ks], acc2[mt][nt], 0, 0, 0);
  }
  // per-row att dots over this wave's 32 cols; reduce across the 16-lane groups
  {
    float ps[3][4], pd[3][4];
    #pragma unroll
    for (int mt = 0; mt < 3; ++mt)
      #pragma unroll
      for (int r = 0; r < 4; ++r) {
        ps[mt][r] = acc2[mt][0][r] * atS[0] + acc2[mt][1][r] * atS[1];
        pd[mt][r] = acc2[mt][0][r] * atD[0] + acc2[mt][1][r] * atD[1];
      }
    #pragma unroll
    for (int off = 1; off < 16; off <<= 1)
      #pragma unroll
      for (int mt = 0; mt < 3; ++mt)
        #pragma unroll
        for (int r = 0; r < 4; ++r) {
          ps[mt][r] += __shfl_xor(ps[mt][r], off);
          pd[mt][r] += __shfl_xor(pd[mt][r], off);
        }
    if (lm == 0) {
      #pragma unroll
      for (int mt = 0; mt < 3; ++mt)
        #pragma unroll
        for (int r = 0; r < 4; ++r) {
          int row = mt * 16 + lq * 4 + r;
          asP[wid][row] = ps[mt][r];
          adP[wid][row] = pd[mt][r];
        }
    }
  }
  __syncthreads();
  if (t < 48) {
    asS[t] = asP[0][t] + asP[1][t] + asP[2][t] + asP[3][t];
    adS[t] = adP[0][t] + adP[1][t] + adP[2][t] + adP[3][t];
  }
  __syncthreads();
  if (t < 48) {  // (node n, dest j): softmax over the 6 group members
    int n = t / 6, nb6 = n * 6;
    float ad = adS[t];
    float s6[6], m = -1e30f;
    #pragma unroll
    for (int i = 0; i < 6; ++i) {
      float s = asS[nb6 + i] + ad;
      s = (s > 0.f) ? s : 0.2f * s;
      s6[i] = s; m = fmaxf(m, s);
    }
    float ssum = 0.f, ex[6];
    #pragma unroll
    for (int i = 0; i < 6; ++i) { ex[i] = __expf(s6[i] - m); ssum += ex[i]; }
    float inv = 1.f / (ssum + 1e-16f);
    #pragma unroll
    for (int i = 0; i < 6; ++i) alphaL[t][i] = ex[i] * inv;
  }
  __syncthreads();
  if (t < 48) {  // w_i = sum_j alpha_ij
    int n = t / 6, i = t % 6;
    float w = 0.f;
    #pragma unroll
    for (int j = 0; j < 6; ++j) w += alphaL[n * 6 + j][i];
    wS[t] = w;
  }
  __syncthreads();
  // pool: h3[n] += w_row * x_row
  #pragma unroll
  for (int mt = 0; mt < 3; ++mt)
    #pragma unroll
    for (int r = 0; r < 4; ++r) {
      int row = mt * 16 + lq * 4 + r;
      float w = wS[row];
      int nl = row / 6;
      #pragma unroll
      for (int nt = 0; nt < 2; ++nt)
        atomicAdd(&h3L[nl * 128 + Nb + nt * 16 + lm], w * acc2[mt][nt][r]);
    }
  __syncthreads();
  // write out + bnf stats (8-way split atomics)
  const int c4 = (t & 31) * 4, nslot = t >> 5;
  f32x4 v = *(f32x4*)&h3L[nslot * 128 + c4];
  const f32x4 gb = *(const f32x4*)&gat_bias[c4];
  v[0] += 6.f * gb[0]; v[1] += 6.f * gb[1];
  v[2] += 6.f * gb[2]; v[3] += 6.f * gb[3];
  *(f32x4*)&out[(blockIdx.x * 8 + nslot) * 128 + c4] = v;
  const int set = blockIdx.x & 7;
  #pragma unroll
  for (int j = 0; j < 4; ++j) red[nslot][c4 + j] = v[j];
  __syncthreads();
  if (t < 128) {
    float s = 0.f;
    #pragma unroll
    for (int k = 0; k < 8; ++k) s += red[k][t];
    atomicAdd(&ws[WS_FSUM + set * 128 + t], s);
  }
  __syncthreads();
  #pragma unroll
  for (int j = 0; j < 4; ++j) red[nslot][c4 + j] = v[j] * v[j];
  __syncthreads();
  if (t < 128) {
    float s = 0.f;
    #pragma unroll
    for (int k = 0; k < 8; ++k) s += red[k][t];
    atomicAdd(&ws[WS_FSQ + set * 128 + t], s);
  }
}

// ------------------------------------------ K4: final BN applied in-place on out
__global__ __launch_bounds__(256) void k4_final(
    float* __restrict__ out, const float* __restrict__ ws,
    const float* __restrict__ bnf_g, const float* __restrict__ bnf_b) {
  int idx4 = blockIdx.x * 256 + threadIdx.x;
  if (idx4 >= N_NODES * 128 / 4) return;
  int c0 = (idx4 & 31) << 2;
  float4 v = ((float4*)out)[idx4];
  float4 fsv = {0.f, 0.f, 0.f, 0.f}, fqv = {0.f, 0.f, 0.f, 0.f};
  #pragma unroll
  for (int s = 0; s < 8; ++s) {
    float4 a = *(const float4*)&ws[WS_FSUM + s * 128 + c0];
    float4 b = *(const float4*)&ws[WS_FSQ + s * 128 + c0];
    fsv.x += a.x; fsv.y += a.y; fsv.z += a.z; fsv.w += a.w;
    fqv.x += b.x; fqv.y += b.y; fqv.z += b.z; fqv.w += b.w;
  }
  float4 g4 = *(const float4*)&bnf_g[c0];
  float4 b4 = *(const float4*)&bnf_b[c0];
  const float invN = 1.f / (float)N_NODES;
  float mu, var, sc;
  mu = fsv.x * invN; var = fqv.x * invN - mu * mu; sc = g4.x * rsqrtf(var + EPS_BN);
  v.x = (v.x - mu) * sc + b4.x;
  mu = fsv.y * invN; var = fqv.y * invN - mu * mu; sc = g4.y * rsqrtf(var + EPS_BN);
  v.y = (v.y - mu) * sc + b4.y;
  mu = fsv.z * invN; var = fqv.z * invN - mu * mu; sc = g4.z * rsqrtf(var + EPS_BN);
  v.z = (v.z - mu) * sc + b4.z;
  mu = fsv.w * invN; var = fqv.w * invN - mu * mu; sc = g4.w * rsqrtf(var + EPS_BN);
  v.w = (v.w - mu) * sc + b4.w;
  ((float4*)out)[idx4] = v;
}

extern "C" void kernel_launch(void* const* d_in, const int* in_sizes, int n_in,
                              void* d_out, int out_size, void* d_ws, size_t ws_size,
                              hipStream_t stream) {
  const float* edge_attr = (const float*)d_in[0];
  const float* node_attr = (const float*)d_in[1];
  const float* bn0_g = (const float*)d_in[2];
  const float* bn0_b = (const float*)d_in[3];
  const float* W1    = (const float*)d_in[4];
  const float* bn1_g = (const float*)d_in[5];
  const float* bn1_b = (const float*)d_in[6];
  const float* Wg    = (const float*)d_in[7];
  const float* att_src = (const float*)d_in[8];
  const float* att_dst = (const float*)d_in[9];
  const float* gat_bias = (const float*)d_in[10];
  const float* bnf_g = (const float*)d_in[11];
  const float* bnf_b = (const float*)d_in[12];
  float* ws = (float*)d_ws;
  float* out = (float*)d_out;

  hipMemsetAsync(d_ws, 0, WS_STATS_FLOATS * sizeof(float), stream);
  k0_prep<<<32, 256, 0, stream>>>(W1, Wg, ws);
  k1_bn0_stats<<<256, 256, 0, stream>>>(node_attr, edge_attr, ws);
  k2_bn1_stats<<<E_EDGES / 48, 256, 0, stream>>>(node_attr, edge_attr, bn0_g, bn0_b, ws);
  k3_fused<<<E_EDGES / 48, 256, 0, stream>>>(node_attr, edge_attr, bn0_g, bn0_b,
                                             bn1_g, bn1_b, att_src, att_dst, gat_bias,
                                             out, ws);
  k4_final<<<2500, 256, 0, stream>>>(out, ws, bnf_g, bnf_b);
}

// Round 10
// 249.827 us; speedup vs baseline: 1.3022x; 1.0006x over previous
//
#include <hip/hip_runtime.h>

#define N_NODES 20000
#define DEG 6
#define E_EDGES 120000
#define EPS_BN 1e-5f
#define NBLK 1250
#define EB 96      // edges per block
#define NB 16      // nodes per block

// ws float offsets
#define WS_S0SUM 0          // 80
#define WS_S0SQ  80         // 80
#define WS_BIAS1 160        // 128
#define WS_S1SUM 288        // 8 sets x 128
#define WS_S1SQ  1312       // 8 sets x 128
#define WS_SC1M  2336       // 128
#define WS_SH1M  2464       // 128
#define WS_FSUM  2592       // 128
#define WS_FSQ   2720       // 128
#define WS_STATS_FLOATS 2848
// bf16 weight tables (written by k0_fold each launch)
#define WS_WT1   2848       // 128 cols x 96 k (bf16) = 6144 floats
#define WS_WGT   8992       // 128 cols x 128 k (bf16) = 8192 floats -> end 17184

typedef float f32x4 __attribute__((ext_vector_type(4)));
typedef short bf16x8 __attribute__((ext_vector_type(8)));

__device__ __forceinline__ unsigned short f2bf(float f) {
  unsigned u = __float_as_uint(f);
  u += 0x7fffu + ((u >> 16) & 1u);   // RNE
  return (unsigned short)(u >> 16);
}
__device__ __forceinline__ unsigned pack2bf(float a, float b) {
  return (unsigned)f2bf(a) | ((unsigned)f2bf(b) << 16);
}

// ---------------------------------------------------------------- K1: bn0 stats
__global__ __launch_bounds__(256) void k1_bn0_stats(
    const float* __restrict__ node_attr, const float* __restrict__ edge_attr,
    float* __restrict__ ws) {
  __shared__ float red[256];
  const int t = threadIdx.x;
  const int b = blockIdx.x;
  if (b < 128) {  // node cols (per-node stats == per-edge stats, exact 6x repeat)
    const int c = t & 63, rl = t >> 6;
    float s = 0.f, q = 0.f;
    for (int row = b * 4 + rl; row < N_NODES; row += 512) {
      float v = node_attr[row * 64 + c];
      s += v; q += v * v;
    }
    red[t] = s;
    __syncthreads();
    if (t < 64) atomicAdd(&ws[WS_S0SUM + t], red[t] + red[t + 64] + red[t + 128] + red[t + 192]);
    __syncthreads();
    red[t] = q;
    __syncthreads();
    if (t < 64) atomicAdd(&ws[WS_S0SQ + t], red[t] + red[t + 64] + red[t + 128] + red[t + 192]);
  } else {  // edge cols
    const int c = t & 15, rl = t >> 4;
    float s = 0.f, q = 0.f;
    for (int row = (b - 128) * 16 + rl; row < E_EDGES; row += 2048) {
      float v = edge_attr[row * 16 + c];
      s += v; q += v * v;
    }
    red[t] = s;
    __syncthreads();
    if (t < 16) {
      float tot = 0.f;
      #pragma unroll
      for (int k = 0; k < 16; ++k) tot += red[t + 16 * k];
      atomicAdd(&ws[WS_S0SUM + 64 + t], tot);
    }
    __syncthreads();
    red[t] = q;
    __syncthreads();
    if (t < 16) {
      float tot = 0.f;
      #pragma unroll
      for (int k = 0; k < 16; ++k) tot += red[t + 16 * k];
      atomicAdd(&ws[WS_S0SQ + 64 + t], tot);
    }
  }
}

// ------------- K0 (after k1): fold bn0 into W1 -> wt1 bf16; bias1; wgt bf16
__global__ __launch_bounds__(256) void k0_fold(
    const float* __restrict__ W1, const float* __restrict__ Wg,
    const float* __restrict__ bn0_g, const float* __restrict__ bn0_b,
    float* __restrict__ ws) {
  short* wt1 = (short*)(ws + WS_WT1);
  short* wgt = (short*)(ws + WS_WGT);
  const int t0 = blockIdx.x * 256 + threadIdx.x;
  for (int i = t0; i < 128 * 96; i += 32 * 256) {
    int n = i / 96, k = i % 96;
    float v = 0.f;
    if (k < 80) {
      float cnt = (k < 64) ? (float)N_NODES : (float)E_EDGES;
      float mu = ws[WS_S0SUM + k] / cnt;
      float var = ws[WS_S0SQ + k] / cnt - mu * mu;
      v = W1[k * 128 + n] * (bn0_g[k] * rsqrtf(var + EPS_BN));
    }
    wt1[i] = (short)f2bf(v);
  }
  for (int i = t0; i < 128 * 128; i += 32 * 256) {
    int n = i >> 7, k = i & 127;
    wgt[i] = (short)f2bf(Wg[k * 128 + n]);
  }
  if (blockIdx.x == 0 && threadIdx.x < 128) {
    int n = threadIdx.x;
    float s = 0.f;
    for (int k = 0; k < 80; ++k) {
      float cnt = (k < 64) ? (float)N_NODES : (float)E_EDGES;
      float mu = ws[WS_S0SUM + k] / cnt;
      float var = ws[WS_S0SQ + k] / cnt - mu * mu;
      float sc = bn0_g[k] * rsqrtf(var + EPS_BN);
      s += (bn0_b[k] - mu * sc) * W1[k * 128 + n];
    }
    ws[WS_BIAS1 + n] = s;
  }
}

// ---- shared staging macro body: raw inputs -> bf16 LDS (coalesced float4)
#define STAGE_INPUTS()                                                         \
  {                                                                            \
    int i = t;                                                                 \
    int row = i >> 4, c4 = (i & 15) << 2;                                      \
    float4 v = *(const float4*)&node_attr[(size_t)(g * NB + row) * 64 + c4];   \
    *(uint2*)&n0s[row * 72 + c4] = make_uint2(pack2bf(v.x, v.y), pack2bf(v.z, v.w)); \
  }                                                                            \
  for (int i = t; i < EB * 4; i += 256) {                                      \
    int row = i >> 2, c4 = (i & 3) << 2;                                       \
    float4 v = *(const float4*)&edge_attr[(size_t)(g * EB + row) * 16 + c4];   \
    *(uint2*)&e0s[row * 24 + c4] = make_uint2(pack2bf(v.x, v.y), pack2bf(v.z, v.w)); \
  }                                                                            \
  if (t < 8) zpad[t] = 0;

// ---- GEMM1 core: acc1[6][2] over K=96 (nodes k0..63, edges 64..79, zeros 80..95)
#define GEMM1_CORE(acc1)                                                       \
  _Pragma("unroll")                                                            \
  for (int ks = 0; ks < 3; ++ks) {                                             \
    bf16x8 bb0 = *(const bf16x8*)&wt1[(Nb + lm) * 96 + ks * 32 + lq * 8];      \
    bf16x8 bb1 = *(const bf16x8*)&wt1[(Nb + 16 + lm) * 96 + ks * 32 + lq * 8]; \
    _Pragma("unroll")                                                          \
    for (int mt = 0; mt < 6; ++mt) {                                           \
      const short* ap;                                                         \
      if (ks < 2) ap = &n0s[rowdiv6[mt] * 72 + ks * 32 + lq * 8];              \
      else ap = (lq < 2) ? &e0s[(mt * 16 + lm) * 24 + lq * 8] : zpad;          \
      bf16x8 a = *(const bf16x8*)ap;                                           \
      acc1[mt][0] = __builtin_amdgcn_mfma_f32_16x16x32_bf16(a, bb0, acc1[mt][0], 0, 0, 0); \
      acc1[mt][1] = __builtin_amdgcn_mfma_f32_16x16x32_bf16(a, bb1, acc1[mt][1], 0, 0, 0); \
    }                                                                          \
  }

// -------- K2: GEMM1 over 96-edge tile -> bn1 column sums (8-way split atomics)
__global__ __launch_bounds__(256, 2) void k2_bn1_stats(
    const float* __restrict__ node_attr, const float* __restrict__ edge_attr,
    float* __restrict__ ws) {
  __shared__ __align__(16) short n0s[16 * 72];
  __shared__ __align__(16) short e0s[96 * 24];
  __shared__ __align__(16) short zpad[8];
  const int t = threadIdx.x;
  const int g = blockIdx.x;
  const int l = t & 63, wid = t >> 6;
  const int lm = l & 15, lq = l >> 4;
  const int Nb = wid * 32;
  const short* wt1 = (const short*)(ws + WS_WT1);
  int rowdiv6[6];
  #pragma unroll
  for (int mt = 0; mt < 6; ++mt) rowdiv6[mt] = (mt * 16 + lm) / 6;
  float bias1c[2];
  bias1c[0] = ws[WS_BIAS1 + Nb + lm];
  bias1c[1] = ws[WS_BIAS1 + Nb + 16 + lm];
  STAGE_INPUTS();
  __syncthreads();
  f32x4 acc1[6][2] = {};
  GEMM1_CORE(acc1);
  const int set = g & 7;
  #pragma unroll
  for (int nt = 0; nt < 2; ++nt) {
    float s = 0.f, q = 0.f;
    #pragma unroll
    for (int mt = 0; mt < 6; ++mt)
      #pragma unroll
      for (int r = 0; r < 4; ++r) {
        float v = acc1[mt][nt][r] + bias1c[nt];
        s += v; q += v * v;
      }
    s += __shfl_xor(s, 16); s += __shfl_xor(s, 32);
    q += __shfl_xor(q, 16); q += __shfl_xor(q, 32);
    if (l < 16) {
      int col = Nb + nt * 16 + lm;
      atomicAdd(&ws[WS_S1SUM + set * 128 + col], s);
      atomicAdd(&ws[WS_S1SQ + set * 128 + col], q);
    }
  }
}

// -------- K2b (1 block): finalize bn1 -> merged affine (sc1m, sh1m)
__global__ __launch_bounds__(128) void k2b_finalize(
    const float* __restrict__ bn1_g, const float* __restrict__ bn1_b,
    float* __restrict__ ws) {
  const int t = threadIdx.x;
  float s = 0.f, q = 0.f;
  #pragma unroll
  for (int st = 0; st < 8; ++st) {
    s += ws[WS_S1SUM + st * 128 + t];
    q += ws[WS_S1SQ + st * 128 + t];
  }
  const float invE = 1.f / (float)E_EDGES;
  float mu = s * invE;
  float var = q * invE - mu * mu;
  float sc1 = bn1_g[t] * rsqrtf(var + EPS_BN);
  float sh1 = bn1_b[t] - mu * sc1;
  ws[WS_SC1M + t] = sc1;
  ws[WS_SH1M + t] = ws[WS_BIAS1 + t] * sc1 + sh1;
}

// ---- K3: 96-edge tile: GEMM1+relu -> GEMM2 -> 6x6 attention -> pool -> out
__global__ __launch_bounds__(256, 2) void k3_fused(
    const float* __restrict__ node_attr, const float* __restrict__ edge_attr,
    const float* __restrict__ att_src, const float* __restrict__ att_dst,
    const float* __restrict__ gat_bias,
    float* __restrict__ out, float* __restrict__ ws) {
  __shared__ __align__(16) short n0s[16 * 72];
  __shared__ __align__(16) short e0s[96 * 24];
  __shared__ __align__(16) short zpad[8];
  __shared__ __align__(16) short h1s[96 * 136];     // 25.5 KB
  __shared__ float asP[4][96], adP[4][96];
  __shared__ float asS[96], adS[96], wS[96];
  __shared__ float alphaL[96][6];
  __shared__ float h3L[16 * 128];                   // 8 KB

  const int t = threadIdx.x;
  const int g = blockIdx.x;
  const int l = t & 63, wid = t >> 6;
  const int lm = l & 15, lq = l >> 4;
  const int Nb = wid * 32;
  const short* wt1 = (const short*)(ws + WS_WT1);
  const short* wgt = (const short*)(ws + WS_WGT);
  int rowdiv6[6];
  #pragma unroll
  for (int mt = 0; mt < 6; ++mt) rowdiv6[mt] = (mt * 16 + lm) / 6;
  float sc1c[2], sh1c[2], atS[2], atD[2];
  #pragma unroll
  for (int nt = 0; nt < 2; ++nt) {
    int col = Nb + nt * 16 + lm;
    sc1c[nt] = ws[WS_SC1M + col];
    sh1c[nt] = ws[WS_SH1M + col];
    atS[nt] = att_src[col];
    atD[nt] = att_dst[col];
  }
  // zero pool buffer
  #pragma unroll
  for (int j = 0; j < 2; ++j)
    *(f32x4*)&h3L[(t + j * 256) * 4] = (f32x4){0.f, 0.f, 0.f, 0.f};
  STAGE_INPUTS();
  __syncthreads();
  // GEMM1 -> merged bn1 affine -> relu -> h1s (bf16)
  {
    f32x4 acc1[6][2] = {};
    GEMM1_CORE(acc1);
    #pragma unroll
    for (int mt = 0; mt < 6; ++mt)
      #pragma unroll
      for (int nt = 0; nt < 2; ++nt)
        #pragma unroll
        for (int r = 0; r < 4; ++r) {
          int row = mt * 16 + lq * 4 + r;
          int col = Nb + nt * 16 + lm;
          float v = fmaxf(acc1[mt][nt][r] * sc1c[nt] + sh1c[nt], 0.f);
          h1s[row * 136 + col] = (short)f2bf(v);
        }
  }
  __syncthreads();
  // GEMM2 (K=128), x kept in registers
  f32x4 acc2[6][2] = {};
  #pragma unroll
  for (int ks = 0; ks < 4; ++ks) {
    bf16x8 bb0 = *(const bf16x8*)&wgt[(Nb + lm) * 128 + ks * 32 + lq * 8];
    bf16x8 bb1 = *(const bf16x8*)&wgt[(Nb + 16 + lm) * 128 + ks * 32 + lq * 8];
    #pragma unroll
    for (int mt = 0; mt < 6; ++mt) {
      bf16x8 a = *(const bf16x8*)&h1s[(mt * 16 + lm) * 136 + ks * 32 + lq * 8];
      acc2[mt][0] = __builtin_amdgcn_mfma_f32_16x16x32_bf16(a, bb0, acc2[mt][0], 0, 0, 0);
      acc2[mt][1] = __builtin_amdgcn_mfma_f32_16x16x32_bf16(a, bb1, acc2[mt][1], 0, 0, 0);
    }
  }
  // per-row att dots over this wave's 32 cols; reduce across the 16-lane groups
  {
    float ps, pd;
    #pragma unroll
    for (int mt = 0; mt < 6; ++mt)
      #pragma unroll
      for (int r = 0; r < 4; ++r) {
        ps = acc2[mt][0][r] * atS[0] + acc2[mt][1][r] * atS[1];
        pd = acc2[mt][0][r] * atD[0] + acc2[mt][1][r] * atD[1];
        #pragma unroll
        for (int off = 1; off < 16; off <<= 1) {
          ps += __shfl_xor(ps, off);
          pd += __shfl_xor(pd, off);
        }
        if (lm == 0) {
          int row = mt * 16 + lq * 4 + r;
          asP[wid][row] = ps;
          adP[wid][row] = pd;
        }
      }
  }
  __syncthreads();
  if (t < 96) {
    asS[t] = asP[0][t] + asP[1][t] + asP[2][t] + asP[3][t];
    adS[t] = adP[0][t] + adP[1][t] + adP[2][t] + adP[3][t];
  }
  __syncthreads();
  if (t < 96) {  // (node n, dest j): softmax over the 6 group members
    int n = t / 6;
    int nb6 = n * 6;
    float ad = adS[t];
    float s6[6], m = -1e30f;
    #pragma unroll
    for (int i = 0; i < 6; ++i) {
      float s = asS[nb6 + i] + ad;
      s = (s > 0.f) ? s : 0.2f * s;
      s6[i] = s; m = fmaxf(m, s);
    }
    float ssum = 0.f, ex[6];
    #pragma unroll
    for (int i = 0; i < 6; ++i) { ex[i] = __expf(s6[i] - m); ssum += ex[i]; }
    float inv = 1.f / (ssum + 1e-16f);
    #pragma unroll
    for (int i = 0; i < 6; ++i) alphaL[t][i] = ex[i] * inv;
  }
  __syncthreads();
  if (t < 96) {  // w_i = sum_j alpha_ij
    int n = t / 6, i = t % 6;
    float w = 0.f;
    #pragma unroll
    for (int j = 0; j < 6; ++j) w += alphaL[n * 6 + j][i];
    wS[t] = w;
  }
  __syncthreads();
  // pool: h3[node] += w_row * x_row
  #pragma unroll
  for (int mt = 0; mt < 6; ++mt)
    #pragma unroll
    for (int r = 0; r < 4; ++r) {
      int row = mt * 16 + lq * 4 + r;
      float w = wS[row];
      int nl = row / 6;
      #pragma unroll
      for (int nt = 0; nt < 2; ++nt)
        atomicAdd(&h3L[nl * 128 + Nb + nt * 16 + lm], w * acc2[mt][nt][r]);
    }
  __syncthreads();
  // write out (+6*gat_bias); no stats here
  #pragma unroll
  for (int j = 0; j < 2; ++j) {
    int idx = t + j * 256;
    int nslot = idx >> 5, c4 = (idx & 31) << 2;
    f32x4 v = *(f32x4*)&h3L[nslot * 128 + c4];
    const f32x4 gb = *(const f32x4*)&gat_bias[c4];
    v[0] += 6.f * gb[0]; v[1] += 6.f * gb[1];
    v[2] += 6.f * gb[2]; v[3] += 6.f * gb[3];
    *(f32x4*)&out[(size_t)(g * NB + nslot) * 128 + c4] = v;
  }
}

// -------- K4a: bnf column stats over out (streaming)
__global__ __launch_bounds__(256) void k4a_stats(
    const float* __restrict__ out, float* __restrict__ ws) {
  __shared__ float red[8][128];
  const int t = threadIdx.x;
  const int c4 = (t & 31) << 2, rl = t >> 5;
  float fs[4] = {0.f, 0.f, 0.f, 0.f}, fq[4] = {0.f, 0.f, 0.f, 0.f};
  for (int r = blockIdx.x * 8 + rl; r < N_NODES; r += 128 * 8) {
    float4 v = *(const float4*)&out[(size_t)r * 128 + c4];
    fs[0] += v.x; fq[0] += v.x * v.x;
    fs[1] += v.y; fq[1] += v.y * v.y;
    fs[2] += v.z; fq[2] += v.z * v.z;
    fs[3] += v.w; fq[3] += v.w * v.w;
  }
  #pragma unroll
  for (int j = 0; j < 4; ++j) red[rl][c4 + j] = fs[j];
  __syncthreads();
  if (t < 128) {
    float s = 0.f;
    #pragma unroll
    for (int k = 0; k < 8; ++k) s += red[k][t];
    atomicAdd(&ws[WS_FSUM + t], s);
  }
  __syncthreads();
  #pragma unroll
  for (int j = 0; j < 4; ++j) red[rl][c4 + j] = fq[j];
  __syncthreads();
  if (t < 128) {
    float s = 0.f;
    #pragma unroll
    for (int k = 0; k < 8; ++k) s += red[k][t];
    atomicAdd(&ws[WS_FSQ + t], s);
  }
}

// -------- K4b: apply final BN in-place
__global__ __launch_bounds__(256) void k4b_apply(
    float* __restrict__ out, const float* __restrict__ ws,
    const float* __restrict__ bnf_g, const float* __restrict__ bnf_b) {
  int idx4 = blockIdx.x * 256 + threadIdx.x;
  if (idx4 >= N_NODES * 128 / 4) return;
  int c0 = (idx4 & 31) << 2;
  float4 v = ((float4*)out)[idx4];
  float4 fsv = *(const float4*)&ws[WS_FSUM + c0];
  float4 fqv = *(const float4*)&ws[WS_FSQ + c0];
  float4 g4 = *(const float4*)&bnf_g[c0];
  float4 b4 = *(const float4*)&bnf_b[c0];
  const float invN = 1.f / (float)N_NODES;
  float mu, var, sc;
  mu = fsv.x * invN; var = fqv.x * invN - mu * mu; sc = g4.x * rsqrtf(var + EPS_BN);
  v.x = (v.x - mu) * sc + b4.x;
  mu = fsv.y * invN; var = fqv.y * invN - mu * mu; sc = g4.y * rsqrtf(var + EPS_BN);
  v.y = (v.y - mu) * sc + b4.y;
  mu = fsv.z * invN; var = fqv.z * invN - mu * mu; sc = g4.z * rsqrtf(var + EPS_BN);
  v.z = (v.z - mu) * sc + b4.z;
  mu = fsv.w * invN; var = fqv.w * invN - mu * mu; sc = g4.w * rsqrtf(var + EPS_BN);
  v.w = (v.w - mu) * sc + b4.w;
  ((float4*)out)[idx4] = v;
}

extern "C" void kernel_launch(void* const* d_in, const int* in_sizes, int n_in,
                              void* d_out, int out_size, void* d_ws, size_t ws_size,
                              hipStream_t stream) {
  const float* edge_attr = (const float*)d_in[0];
  const float* node_attr = (const float*)d_in[1];
  const float* bn0_g = (const float*)d_in[2];
  const float* bn0_b = (const float*)d_in[3];
  const float* W1    = (const float*)d_in[4];
  const float* bn1_g = (const float*)d_in[5];
  const float* bn1_b = (const float*)d_in[6];
  const float* Wg    = (const float*)d_in[7];
  const float* att_src = (const float*)d_in[8];
  const float* att_dst = (const float*)d_in[9];
  const float* gat_bias = (const float*)d_in[10];
  const float* bnf_g = (const float*)d_in[11];
  const float* bnf_b = (const float*)d_in[12];
  float* ws = (float*)d_ws;
  float* out = (float*)d_out;

  hipMemsetAsync(d_ws, 0, WS_STATS_FLOATS * sizeof(float), stream);
  k1_bn0_stats<<<256, 256, 0, stream>>>(node_attr, edge_attr, ws);
  k0_fold<<<32, 256, 0, stream>>>(W1, Wg, bn0_g, bn0_b, ws);
  k2_bn1_stats<<<NBLK, 256, 0, stream>>>(node_attr, edge_attr, ws);
  k2b_finalize<<<1, 128, 0, stream>>>(bn1_g, bn1_b, ws);
  k3_fused<<<NBLK, 256, 0, stream>>>(node_attr, edge_attr, att_src, att_dst,
                                     gat_bias, out, ws);
  k4a_stats<<<128, 256, 0, stream>>>(out, ws);
  k4b_apply<<<2500, 256, 0, stream>>>(out, ws, bnf_g, bnf_b);
}